// Round 22
// baseline (140.121 us; speedup 1.0000x reference)
//
#include <hip/hip_runtime.h>
#include <hip/hip_bf16.h>

// Inputs: 0 features[N,64] f32 | 1 receivers[E] i32 | 2 relpos[E,2] f32
//         3 window_support[1] f32 | 4 senders[E] i32 | 5 kernel[4,2,64,64] f32
//         6 bias[64] f32   -> out [N,64] f32

#define T_TAPS 16
#define BUCKET 64   // max edges per receiver (Poisson(16): P(deg>64) ~ 1e-20)

typedef unsigned short u16;
typedef short s16x8 __attribute__((ext_vector_type(8)));
typedef u16 u16x8 __attribute__((ext_vector_type(8)));
typedef float f32x2 __attribute__((ext_vector_type(2)));
typedef float f32x4 __attribute__((ext_vector_type(4)));

static __device__ __forceinline__ u16 f2bf(float x) {
    union { float f; unsigned u; } v; v.f = x;
    unsigned r = v.u + 0x7FFF + ((v.u >> 16) & 1);
    return (u16)(r >> 16);
}

// async global->LDS 16B copy (wave-uniform LDS base + lane*16)
#define GLDS16(src, dst) __builtin_amdgcn_global_load_lds(                      \
    (const __attribute__((address_space(1))) unsigned*)(src),                   \
    (__attribute__((address_space(3))) unsigned*)(dst), 16, 0, 0)

// pre-swizzle a byte offset within its 256-B chunk: XOR bits 4..7 with (row&7)<<4
static __device__ __forceinline__ int swz(int b, int row) {
    return (b & ~255) | ((b & 255) ^ ((row & 7) << 4));
}

// ---------------- setup: KfT build (PRE-SWIZZLED) + zero(cnt) ----------------
// KfT row o (2048 B): k = i*16 + t ; byte k*2 stored at swz(k*2, o).
__global__ __launch_bounds__(256) void ascc_setup(
    u16* __restrict__ KfT, const float* __restrict__ kern,
    int* __restrict__ cnt, int Nn)
{
    int b = blockIdx.x;
    if (b < 256) {
        int idx = b * 256 + threadIdx.x;   // 64*1024
        int o = idx >> 10;
        int k = idx & 1023;
        int i = k >> 4, t = k & 15;
        int x = t >> 2, y = t & 3;
        float val;
        if (y < 2) val =  kern[(((x * 2 + y) * 64) + i) * 64 + o];
        else       val = -kern[((((3 - x) * 2 + (3 - y)) * 64) + i) * 64 + o];
        *(u16*)((char*)KfT + ((size_t)o << 11) + swz(k * 2, o)) = f2bf(val);
    } else {
        int i = (b - 256) * 256 + threadIdx.x;
        if (i < Nn) cnt[i] = 0;
    }
}

// ---------- fillprep: 4 edges/thread, ONE 16-B record per edge --------------
// rec[r*BUCKET+p] = { wxl*win f32, wxh*win f32,
//                     bf16(wyl)<<16 | bf16(wyh),  sender | x0<<28 | y0<<30 }
// wxl=1-fx at row x0, wxh=fx at x0+1; wyl=1-fy at col y0, wyh=fy at y0+1.
__global__ __launch_bounds__(256) void ascc_fillprep(
    float4* __restrict__ rec,
    int* __restrict__ cnt, const int* __restrict__ receivers,
    const float* __restrict__ relpos, const float* __restrict__ wsup,
    const int* __restrict__ senders, int E)
{
    int base = (blockIdx.x * 256 + threadIdx.x) * 4;
    if (base >= E) return;
    int nv = E - base; nv = (nv < 4) ? nv : 4;
    float ws = wsup[0];

    int rr[4], ss[4], pp[4];
    float2 rp[4];
    #pragma unroll
    for (int q = 0; q < 4; ++q) {
        int e = base + ((q < nv) ? q : 0);
        rr[q] = receivers[e];
        ss[q] = senders[e];
        rp[q] = *(const float2*)(relpos + 2 * e);
    }
    #pragma unroll
    for (int q = 0; q < 4; ++q)
        if (q < nv) pp[q] = atomicAdd(&cnt[rr[q]], 1);

    #pragma unroll
    for (int q = 0; q < 4; ++q) {
        if (q >= nv) break;
        float u0 = fminf(fmaxf(rp[q].x / ws, -1.f), 1.f);
        float u1 = fminf(fmaxf(rp[q].y / ws, -1.f), 1.f);
        float gx = (u0 + 1.f) * 1.5f;
        float gy = (u1 + 1.f) * 1.5f;
        float x0f = fminf(fmaxf(floorf(gx), 0.f), 2.f);
        float y0f = fminf(fmaxf(floorf(gy), 0.f), 2.f);
        float fx = gx - x0f, fy = gy - y0f;
        int x0i = (int)x0f, y0i = (int)y0f;
        float r2 = u0 * u0 + u1 * u1;
        float win = fmaxf(1.f - r2, 0.f);
        win = win * win * win;

        unsigned w2 = ((unsigned)f2bf(1.f - fy) << 16) | (unsigned)f2bf(fy);
        unsigned w3 = (unsigned)ss[q] | ((unsigned)x0i << 28) | ((unsigned)y0i << 30);

        if (pp[q] < BUCKET) {
            rec[(size_t)rr[q] * BUCKET + pp[q]] = make_float4(
                win * (1.f - fx), win * fx,
                __uint_as_float(w2), __uint_as_float(w3));
        }
    }
}

// ---------------- Phase 1: per-receiver register accumulation -> bf16 A -----
// R14-proven structure: one wave per receiver, 4-deep masked groups, records
// scalar-promoted (1 s_load_dwordx4/edge). Weight 4-slot forms reconstructed
// UNIFORM-FIRST: all selects on SGPR values with wave-uniform conditions
// (scalar s_cselect pipe) BEFORE multiplying by per-lane g. VALU per edge is
// unchanged vs R19 (2 pk_mul + 8 pk_fma; the wy3 subs are gone).
// A row stored PRE-SWIZZLED (swz per 256-B chunk) for mgemm's async staging.
__global__ __launch_bounds__(256) void ascc_accum(
    u16* __restrict__ Abf,
    const float* __restrict__ features,
    const int* __restrict__ cnt,
    const float4* __restrict__ rec,
    int Nn)
{
    int lane = threadIdx.x & 63;
    int rv = blockIdx.x * 4 + (threadIdx.x >> 6);
    if (rv >= Nn) return;
    const int r = __builtin_amdgcn_readfirstlane(rv);   // wave-uniform receiver

    f32x2 acc[8];   // [tx*2 + p], p pairs ty {0,1} and {2,3}
    #pragma unroll
    for (int t = 0; t < 8; ++t) acc[t] = (f32x2){0.f, 0.f};

    int n = cnt[r];
    n = (n < BUCKET) ? n : BUCKET;
    const float4* rbase = rec + (size_t)r * BUCKET;

    #pragma unroll 1
    for (int j = 0; j < n; j += 4) {
        // wave-uniform record loads (scalar pipe, 1 dwordx4/edge)
        float4 ra[4];
        #pragma unroll
        for (int q = 0; q < 4; ++q) {
            int jj = j + q;
            int jc = (jj < n) ? jj : (n - 1);
            ra[q] = rbase[jc];
        }
        // per-lane feature gathers, 32-bit indexing
        float g[4];
        #pragma unroll
        for (int q = 0; q < 4; ++q) {
            int s = (int)(__float_as_uint(ra[q].w) & 0x0FFFFFFFu);
            float gg = features[s * 64 + lane];
            g[q] = (j + q < n) ? gg : 0.f;
        }
        #pragma unroll
        for (int q = 0; q < 4; ++q) {
            unsigned w2 = __float_as_uint(ra[q].z);
            unsigned w3 = __float_as_uint(ra[q].w);
            int x0 = (int)((w3 >> 28) & 3u);
            int y0 = (int)(w3 >> 30);
            // uniform bf16->f32 (bit ops) and uniform 4-slot selects (SALU)
            float wyl = __uint_as_float(w2 & 0xFFFF0000u);
            float wyh = __uint_as_float(w2 << 16);
            float wy0 = (y0 == 0) ? wyl : 0.f;
            float wy1 = (y0 == 0) ? wyh : ((y0 == 1) ? wyl : 0.f);
            float wy2 = (y0 == 1) ? wyh : ((y0 == 2) ? wyl : 0.f);
            float wy3 = (y0 == 2) ? wyh : 0.f;
            float wxl = ra[q].x, wxh = ra[q].y;
            float wx0 = (x0 == 0) ? wxl : 0.f;
            float wx1 = (x0 == 0) ? wxh : ((x0 == 1) ? wxl : 0.f);
            float wx2 = (x0 == 1) ? wxh : ((x0 == 2) ? wxl : 0.f);
            float wx3 = (x0 == 2) ? wxh : 0.f;
            // per-lane part: 2 pk_mul + 8 pk_fma
            f32x2 wyg01 = {wy0 * g[q], wy1 * g[q]};
            f32x2 wyg23 = {wy2 * g[q], wy3 * g[q]};
            acc[0] += wx0 * wyg01;  acc[1] += wx0 * wyg23;
            acc[2] += wx1 * wyg01;  acc[3] += wx1 * wyg23;
            acc[4] += wx2 * wyg01;  acc[5] += wx2 * wyg23;
            acc[6] += wx3 * wyg01;  acc[7] += wx3 * wyg23;
        }
    }

    // tap t = tx*4+ty ; value = acc[tx*2 + (ty>>1)][ty&1]
    u16x8 lo, hi;
    #pragma unroll
    for (int t = 0; t < 8; ++t)  lo[t] = f2bf(acc[(t >> 2) * 2 + ((t & 3) >> 1)][t & 1]);
    #pragma unroll
    for (int t = 0; t < 8; ++t)  hi[t] = f2bf(acc[(2 + (t >> 2)) * 2 + ((t & 3) >> 1)][t & 1]);
    // row bytes: b0 = lane*32 (taps 0..7 of ch=lane), b1 = b0+16; store swizzled
    char* rowp = (char*)Abf + ((size_t)r << 11);
    int b0 = lane << 5;
    *(u16x8*)(rowp + swz(b0, r)) = lo;
    *(u16x8*)(rowp + swz(b0 + 16, r)) = hi;
}

// ---------------- Phase 2: MFMA GEMM out[N,64] = A[N,1024] * Kf[1024,64] ----
// A and B staged via async global_load_lds (16B, linear LDS dest); sources
// are PRE-SWIZZLED in global, so the swizzled ds_read_b128s are unchanged.
__global__ __launch_bounds__(256) void ascc_mgemm(
    float* __restrict__ out,
    const u16* __restrict__ Abf,
    const u16* __restrict__ KfT,
    const float* __restrict__ bias,
    int Nn)
{
    __shared__ u16 Al[64 * 128];   // 16 KB
    __shared__ u16 Bl[64 * 128];   // 16 KB

    const int tid = threadIdx.x;
    const int lane = tid & 63;
    const int w = tid >> 6;
    const int n0 = blockIdx.x * 64;

    f32x4 acc[4] = {};

    for (int kc = 0; kc < 1024; kc += 128) {
        __syncthreads();
        // stage A+B: per wave, 4x 1KB async copies each (LDS linear, src pre-swz)
        #pragma unroll
        for (int it = 0; it < 4; ++it) {
            int beta = (w << 12) + (it << 10) + (lane << 4);   // LDS byte offset
            int row = beta >> 8;                                // 0..63
            int within = beta & 255;
            const char* srcA = (const char*)Abf + (((size_t)(n0 + row)) << 11) + (kc << 1) + within;
            GLDS16(srcA, (char*)Al + (w << 12) + (it << 10));
            const char* srcB = (const char*)KfT + (((size_t)row) << 11) + (kc << 1) + within;
            GLDS16(srcB, (char*)Bl + (w << 12) + (it << 10));
        }
        __syncthreads();
        int wr = w << 4;
        #pragma unroll
        for (int ks = 0; ks < 4; ++ks) {
            int arow = wr + (lane & 15);
            int kb = ks * 64 + ((lane >> 4) << 4);
            s16x8 af = *(const s16x8*)((char*)Al + arow * 256 + (kb ^ ((arow & 7) << 4)));
            #pragma unroll
            for (int t = 0; t < 4; ++t) {
                int brow = (t << 4) + (lane & 15);
                s16x8 bf = *(const s16x8*)((char*)Bl + brow * 256 + (kb ^ ((brow & 7) << 4)));
                acc[t] = __builtin_amdgcn_mfma_f32_16x16x32_bf16(af, bf, acc[t], 0, 0, 0);
            }
        }
    }

    int rbase = n0 + (w << 4) + ((lane >> 4) << 2);
    #pragma unroll
    for (int t = 0; t < 4; ++t) {
        int col = (t << 4) + (lane & 15);
        float bv = bias[col];
        #pragma unroll
        for (int reg = 0; reg < 4; ++reg) {
            int n = rbase + reg;
            if (n < Nn) out[(size_t)n * 64 + col] = acc[t][reg] + bv;
        }
    }
}

extern "C" void kernel_launch(void* const* d_in, const int* in_sizes, int n_in,
                              void* d_out, int out_size, void* d_ws, size_t ws_size,
                              hipStream_t stream) {
    const float* features  = (const float*)d_in[0];
    const int*   receivers = (const int*)d_in[1];
    const float* relpos    = (const float*)d_in[2];
    const float* wsup      = (const float*)d_in[3];
    const int*   senders   = (const int*)d_in[4];
    const float* kern      = (const float*)d_in[5];
    const float* bias      = (const float*)d_in[6];
    float* out = (float*)d_out;

    const int Nn = in_sizes[0] / 64;
    const int E  = in_sizes[1];
    const int Nnp = (Nn + 63) & ~63;   // pad A rows to tile multiple (OOB rows = garbage, masked)

    // ws: cnt[N] | rec[N*BUCKET 16B] | KfT | Abf (padded)
    char* wp = (char*)d_ws;
    size_t p = 0;
    auto take = [&](size_t bytes) { char* q = wp + p; p = (p + bytes + 255) & ~(size_t)255; return q; };
    int*    cnt = (int*)take((size_t)Nn * 4);
    float4* rec = (float4*)take((size_t)Nn * BUCKET * 16);
    u16*    KfT = (u16*)take((size_t)64 * 1024 * 2);
    u16*    Abf = (u16*)take((size_t)Nnp * 1024 * 2);
    (void)ws_size;

    ascc_setup<<<dim3(256 + (Nn + 255) / 256), dim3(256), 0, stream>>>(KfT, kern, cnt, Nn);
    ascc_fillprep<<<dim3((E / 4 + 255) / 256), dim3(256), 0, stream>>>(
        rec, cnt, receivers, relpos, wsup, senders, E);
    ascc_accum<<<dim3((Nn + 3) / 4), dim3(256), 0, stream>>>(
        Abf, features, cnt, rec, Nn);
    ascc_mgemm<<<dim3((Nn + 63) / 64), dim3(256), 0, stream>>>(
        out, Abf, KfT, bias, Nn);
}

// Round 23
// 127.903 us; speedup vs baseline: 1.0955x; 1.0955x over previous
//
#include <hip/hip_runtime.h>
#include <hip/hip_bf16.h>

// Inputs: 0 features[N,64] f32 | 1 receivers[E] i32 | 2 relpos[E,2] f32
//         3 window_support[1] f32 | 4 senders[E] i32 | 5 kernel[4,2,64,64] f32
//         6 bias[64] f32   -> out [N,64] f32

#define T_TAPS 16
#define BUCKET 64   // max edges per receiver (Poisson(16): P(deg>64) ~ 1e-20)

typedef unsigned short u16;
typedef short s16x8 __attribute__((ext_vector_type(8)));
typedef u16 u16x8 __attribute__((ext_vector_type(8)));
typedef float f32x2 __attribute__((ext_vector_type(2)));
typedef float f32x4 __attribute__((ext_vector_type(4)));

static __device__ __forceinline__ u16 f2bf(float x) {
    union { float f; unsigned u; } v; v.f = x;
    unsigned r = v.u + 0x7FFF + ((v.u >> 16) & 1);
    return (u16)(r >> 16);
}

// async global->LDS 16B copy (wave-uniform LDS base + lane*16)
#define GLDS16(src, dst) __builtin_amdgcn_global_load_lds(                      \
    (const __attribute__((address_space(1))) unsigned*)(src),                   \
    (__attribute__((address_space(3))) unsigned*)(dst), 16, 0, 0)

// pre-swizzle a byte offset within its 256-B chunk: XOR bits 4..7 with (row&7)<<4
static __device__ __forceinline__ int swz(int b, int row) {
    return (b & ~255) | ((b & 255) ^ ((row & 7) << 4));
}

// ---------------- setup: KfT build (PRE-SWIZZLED) + zero(cnt) ----------------
// KfT row o (2048 B): k = i*16 + t ; byte k*2 stored at swz(k*2, o).
__global__ __launch_bounds__(256) void ascc_setup(
    u16* __restrict__ KfT, const float* __restrict__ kern,
    int* __restrict__ cnt, int Nn)
{
    int b = blockIdx.x;
    if (b < 256) {
        int idx = b * 256 + threadIdx.x;   // 64*1024
        int o = idx >> 10;
        int k = idx & 1023;
        int i = k >> 4, t = k & 15;
        int x = t >> 2, y = t & 3;
        float val;
        if (y < 2) val =  kern[(((x * 2 + y) * 64) + i) * 64 + o];
        else       val = -kern[((((3 - x) * 2 + (3 - y)) * 64) + i) * 64 + o];
        *(u16*)((char*)KfT + ((size_t)o << 11) + swz(k * 2, o)) = f2bf(val);
    } else {
        int i = (b - 256) * 256 + threadIdx.x;
        if (i < Nn) cnt[i] = 0;
    }
}

// ---------- fillprep: claim bucket slot, write one 32-B record --------------
// rec[2*slot]   = (wx0,wx1,wx2,wx3) * win
// rec[2*slot+1] = (wy0,wy1,wy2, bitcast(sender)); wy3 = 1-wy0-wy1-wy2
__global__ __launch_bounds__(256) void ascc_fillprep(
    float4* __restrict__ rec,
    int* __restrict__ cnt, const int* __restrict__ receivers,
    const float* __restrict__ relpos, const float* __restrict__ wsup,
    const int* __restrict__ senders, int E)
{
    int e = blockIdx.x * 256 + threadIdx.x;
    if (e >= E) return;
    int r = receivers[e];
    int p = atomicAdd(&cnt[r], 1);
    if (p >= BUCKET) return;   // statistically unreachable

    float ws = wsup[0];
    float2 rp = *(const float2*)(relpos + 2 * e);
    float u0 = fminf(fmaxf(rp.x / ws, -1.f), 1.f);
    float u1 = fminf(fmaxf(rp.y / ws, -1.f), 1.f);
    float gx = (u0 + 1.f) * 1.5f;
    float gy = (u1 + 1.f) * 1.5f;
    float x0f = fminf(fmaxf(floorf(gx), 0.f), 2.f);
    float y0f = fminf(fmaxf(floorf(gy), 0.f), 2.f);
    float fx = gx - x0f, fy = gy - y0f;
    int x0i = (int)x0f, y0i = (int)y0f;
    float r2 = u0 * u0 + u1 * u1;
    float win = fmaxf(1.f - r2, 0.f);
    win = win * win * win;
    float wx[4], wy[4];
    #pragma unroll
    for (int k = 0; k < 4; ++k)
        wx[k] = win * ((k == x0i) ? (1.f - fx) : ((k == x0i + 1) ? fx : 0.f));
    #pragma unroll
    for (int k = 0; k < 4; ++k)
        wy[k] = (k == y0i) ? (1.f - fy) : ((k == y0i + 1) ? fy : 0.f);

    union { int i; float f; } sv; sv.i = senders[e];
    size_t slot = (size_t)r * BUCKET + p;
    rec[2 * slot]     = make_float4(wx[0], wx[1], wx[2], wx[3]);
    rec[2 * slot + 1] = make_float4(wy[0], wy[1], wy[2], sv.f);
}

// ---------------- Phase 1: per-receiver register accumulation -> bf16 A -----
// R14-proven loop: one wave per receiver, 4-deep masked groups, records
// scalar-promoted via readfirstlane, f32 gathers, 32-bit indexing, packed
// f32x2 accumulation. A row stored PRE-SWIZZLED (swz per 256-B chunk).
__global__ __launch_bounds__(256) void ascc_accum(
    u16* __restrict__ Abf,
    const float* __restrict__ features,
    const int* __restrict__ cnt,
    const float4* __restrict__ rec,
    int Nn)
{
    int lane = threadIdx.x & 63;
    int rv = blockIdx.x * 4 + (threadIdx.x >> 6);
    if (rv >= Nn) return;
    const int r = __builtin_amdgcn_readfirstlane(rv);   // wave-uniform receiver

    f32x2 acc[8];   // [tx*2 + p], p pairs ty {0,1} and {2,3}
    #pragma unroll
    for (int t = 0; t < 8; ++t) acc[t] = (f32x2){0.f, 0.f};

    int n = cnt[r];
    n = (n < BUCKET) ? n : BUCKET;
    const float4* rbase = rec + (size_t)r * (2 * BUCKET);

    #pragma unroll 1
    for (int j = 0; j < n; j += 4) {
        // wave-uniform record loads (scalar pipe)
        float4 ra[4], rb[4];
        #pragma unroll
        for (int q = 0; q < 4; ++q) {
            int jj = j + q;
            int jc = (jj < n) ? jj : (n - 1);
            ra[q] = rbase[2 * jc];
            rb[q] = rbase[2 * jc + 1];
        }
        // per-lane feature gathers, 32-bit indexing
        float g[4];
        #pragma unroll
        for (int q = 0; q < 4; ++q) {
            int s = __float_as_int(rb[q].w);
            float gg = features[s * 64 + lane];
            g[q] = (j + q < n) ? gg : 0.f;
        }
        #pragma unroll
        for (int q = 0; q < 4; ++q) {
            float wy3 = 1.f - rb[q].x - rb[q].y - rb[q].z;
            f32x2 wyg01 = {rb[q].x * g[q], rb[q].y * g[q]};
            f32x2 wyg23 = {rb[q].z * g[q], wy3 * g[q]};
            #pragma unroll
            for (int tx = 0; tx < 4; ++tx) {
                float wxa = (tx == 0) ? ra[q].x : (tx == 1) ? ra[q].y
                          : (tx == 2) ? ra[q].z : ra[q].w;
                acc[tx * 2]     += wxa * wyg01;
                acc[tx * 2 + 1] += wxa * wyg23;
            }
        }
    }

    // tap t = tx*4+ty ; value = acc[tx*2 + (ty>>1)][ty&1]
    u16x8 lo, hi;
    #pragma unroll
    for (int t = 0; t < 8; ++t)  lo[t] = f2bf(acc[(t >> 2) * 2 + ((t & 3) >> 1)][t & 1]);
    #pragma unroll
    for (int t = 0; t < 8; ++t)  hi[t] = f2bf(acc[(2 + (t >> 2)) * 2 + ((t & 3) >> 1)][t & 1]);
    // row bytes: b0 = lane*32 (taps 0..7 of ch=lane), b1 = b0+16; store swizzled
    char* rowp = (char*)Abf + ((size_t)r << 11);
    int b0 = lane << 5;
    *(u16x8*)(rowp + swz(b0, r)) = lo;
    *(u16x8*)(rowp + swz(b0 + 16, r)) = hi;
}

// ---------------- Phase 2: MFMA GEMM out[N,64] = A[N,1024] * Kf[1024,64] ----
// A and B staged via async global_load_lds (16B, linear LDS dest); sources
// are PRE-SWIZZLED in global, so the swizzled ds_read_b128s are unchanged.
__global__ __launch_bounds__(256) void ascc_mgemm(
    float* __restrict__ out,
    const u16* __restrict__ Abf,
    const u16* __restrict__ KfT,
    const float* __restrict__ bias,
    int Nn)
{
    __shared__ u16 Al[64 * 128];   // 16 KB
    __shared__ u16 Bl[64 * 128];   // 16 KB

    const int tid = threadIdx.x;
    const int lane = tid & 63;
    const int w = tid >> 6;
    const int n0 = blockIdx.x * 64;

    f32x4 acc[4] = {};

    for (int kc = 0; kc < 1024; kc += 128) {
        __syncthreads();
        // stage A+B: per wave, 4x 1KB async copies each (LDS linear, src pre-swz)
        #pragma unroll
        for (int it = 0; it < 4; ++it) {
            int beta = (w << 12) + (it << 10) + (lane << 4);   // LDS byte offset
            int row = beta >> 8;                                // 0..63
            int within = beta & 255;
            const char* srcA = (const char*)Abf + (((size_t)(n0 + row)) << 11) + (kc << 1) + within;
            GLDS16(srcA, (char*)Al + (w << 12) + (it << 10));
            const char* srcB = (const char*)KfT + (((size_t)row) << 11) + (kc << 1) + within;
            GLDS16(srcB, (char*)Bl + (w << 12) + (it << 10));
        }
        __syncthreads();
        int wr = w << 4;
        #pragma unroll
        for (int ks = 0; ks < 4; ++ks) {
            int arow = wr + (lane & 15);
            int kb = ks * 64 + ((lane >> 4) << 4);
            s16x8 af = *(const s16x8*)((char*)Al + arow * 256 + (kb ^ ((arow & 7) << 4)));
            #pragma unroll
            for (int t = 0; t < 4; ++t) {
                int brow = (t << 4) + (lane & 15);
                s16x8 bf = *(const s16x8*)((char*)Bl + brow * 256 + (kb ^ ((brow & 7) << 4)));
                acc[t] = __builtin_amdgcn_mfma_f32_16x16x32_bf16(af, bf, acc[t], 0, 0, 0);
            }
        }
    }

    int rbase = n0 + (w << 4) + ((lane >> 4) << 2);
    #pragma unroll
    for (int t = 0; t < 4; ++t) {
        int col = (t << 4) + (lane & 15);
        float bv = bias[col];
        #pragma unroll
        for (int reg = 0; reg < 4; ++reg) {
            int n = rbase + reg;
            if (n < Nn) out[(size_t)n * 64 + col] = acc[t][reg] + bv;
        }
    }
}

extern "C" void kernel_launch(void* const* d_in, const int* in_sizes, int n_in,
                              void* d_out, int out_size, void* d_ws, size_t ws_size,
                              hipStream_t stream) {
    const float* features  = (const float*)d_in[0];
    const int*   receivers = (const int*)d_in[1];
    const float* relpos    = (const float*)d_in[2];
    const float* wsup      = (const float*)d_in[3];
    const int*   senders   = (const int*)d_in[4];
    const float* kern      = (const float*)d_in[5];
    const float* bias      = (const float*)d_in[6];
    float* out = (float*)d_out;

    const int Nn = in_sizes[0] / 64;
    const int E  = in_sizes[1];
    const int Nnp = (Nn + 63) & ~63;   // pad A rows to tile multiple (OOB rows = garbage, masked)

    // ws: cnt[N] | rec[N*BUCKET*2 float4] | KfT | Abf (padded)
    char* wp = (char*)d_ws;
    size_t p = 0;
    auto take = [&](size_t bytes) { char* q = wp + p; p = (p + bytes + 255) & ~(size_t)255; return q; };
    int*    cnt = (int*)take((size_t)Nn * 4);
    float4* rec = (float4*)take((size_t)Nn * BUCKET * 32);
    u16*    KfT = (u16*)take((size_t)64 * 1024 * 2);
    u16*    Abf = (u16*)take((size_t)Nnp * 1024 * 2);
    (void)ws_size;

    ascc_setup<<<dim3(256 + (Nn + 255) / 256), dim3(256), 0, stream>>>(KfT, kern, cnt, Nn);
    ascc_fillprep<<<dim3((E + 255) / 256), dim3(256), 0, stream>>>(
        rec, cnt, receivers, relpos, wsup, senders, E);
    ascc_accum<<<dim3((Nn + 3) / 4), dim3(256), 0, stream>>>(
        Abf, features, cnt, rec, Nn);
    ascc_mgemm<<<dim3((Nn + 63) / 64), dim3(256), 0, stream>>>(
        out, Abf, KfT, bias, Nn);
}